// Round 4
// baseline (82.029 us; speedup 1.0000x reference)
//
#include <hip/hip_runtime.h>
#include <math.h>

#define Bq 2048
#define Nn 1024
#define Dd 128
#define Cc 10
#define BB 4           // batch rows per block
#define NTHREADS 512   // 8 waves
#define NBLK (Bq / BB)               // 512 dist-blocks
#define PART_FLOATS (NBLK * Nn * Cc) // 5.24M floats = 21 MB

// d_out layout (floats): [0, B*C) = labels[bmu]; [B*C, B*C+N*C) = activities; last C = counts
#define ACT_OFF (Bq * Cc)
#define CNT_OFF (Bq * Cc + Nn * Cc)

// ws layout (floats): [0, PART) = partials; [PART, PART+Bq) = cls ints;
// then 16B-aligned: nT4 = 32*1024 float4 (512 KB)
#define WS_CLS_OFF PART_FLOATS
#define WS_NT_OFF  ((PART_FLOATS + Bq + 3) & ~3)
#define WS_NEED_FLOATS (WS_NT_OFF + 32 * Nn * 4)

// ---------------- transpose neurons [N][D] -> nT4[dc][n] (float4 of 4 d's) ----------------
__global__ __launch_bounds__(256) void som_prep(
    const float* __restrict__ neurons,
    float4* __restrict__ nt)   // [32][Nn]
{
    __shared__ float tile[32][129];
    const int t    = threadIdx.x;
    const int base = blockIdx.x * 32;   // 32 rows per block

    #pragma unroll
    for (int k = 0; k < 4; ++k) {
        int i  = t + k * 256;           // float4 index in [0,1024)
        int r  = i >> 5;                // row 0..31
        int c4 = i & 31;                // float4-col 0..31
        float4 v = *(const float4*)&neurons[(long)(base + r) * Dd + c4 * 4];
        tile[r][c4 * 4 + 0] = v.x;
        tile[r][c4 * 4 + 1] = v.y;
        tile[r][c4 * 4 + 2] = v.z;
        tile[r][c4 * 4 + 3] = v.w;
    }
    __syncthreads();

    #pragma unroll
    for (int k = 0; k < 4; ++k) {
        int i  = t + k * 256;
        int dc = i >> 5;                // 0..31
        int r  = i & 31;                // consecutive lanes -> consecutive n
        float4 v;
        v.x = tile[r][dc * 4 + 0];
        v.y = tile[r][dc * 4 + 1];
        v.z = tile[r][dc * 4 + 2];
        v.w = tile[r][dc * 4 + 3];
        nt[dc * Nn + base + r] = v;
    }
}

// ---------------- main distance kernel ----------------
__global__ __launch_bounds__(NTHREADS, 4) void som_dist(
    const float* __restrict__ x,
    const float* __restrict__ y,
    const float4* __restrict__ nt,    // [32][Nn]
    const float* __restrict__ labels,
    const float* __restrict__ sigma,
    float* __restrict__ out,
    float* __restrict__ ws_p,     // [NBLK][Cc][Nn]
    int*   __restrict__ ws_cls)   // [Bq]
{
    __shared__ float xs[BB][Dd];        // 2 KB
    __shared__ float candv[8][BB];
    __shared__ int   candi[8][BB];
    __shared__ float bmu_d[BB];
    __shared__ int   bmu_i[BB];
    __shared__ int   clss[BB];

    const int t  = threadIdx.x;
    const int b0 = blockIdx.x * BB;

    // stage x rows (one element per thread)
    xs[t >> 7][t & (Dd - 1)] = x[b0 * Dd + t];
    __syncthreads();

    // thread owns neurons n0 = t, n1 = t + 512
    float acc0[BB], acc1[BB];
    #pragma unroll
    for (int b = 0; b < BB; ++b) { acc0[b] = 0.f; acc1[b] = 0.f; }

    // software-pipelined dc loop: prefetch next-dc neuron chunks
    float4 nv0 = nt[t];
    float4 nv1 = nt[t + 512];
    #pragma unroll 2
    for (int dc = 0; dc < Dd / 4; ++dc) {
        float4 p0, p1;
        if (dc + 1 < Dd / 4) {
            p0 = nt[(dc + 1) * Nn + t];
            p1 = nt[(dc + 1) * Nn + t + 512];
        }
        #pragma unroll
        for (int b = 0; b < BB; ++b) {
            float4 xv = *(const float4*)&xs[b][dc * 4];  // LDS broadcast
            float d;
            d = xv.x - nv0.x; acc0[b] = fmaf(d, d, acc0[b]);
            d = xv.y - nv0.y; acc0[b] = fmaf(d, d, acc0[b]);
            d = xv.z - nv0.z; acc0[b] = fmaf(d, d, acc0[b]);
            d = xv.w - nv0.w; acc0[b] = fmaf(d, d, acc0[b]);
            d = xv.x - nv1.x; acc1[b] = fmaf(d, d, acc1[b]);
            d = xv.y - nv1.y; acc1[b] = fmaf(d, d, acc1[b]);
            d = xv.z - nv1.z; acc1[b] = fmaf(d, d, acc1[b]);
            d = xv.w - nv1.w; acc1[b] = fmaf(d, d, acc1[b]);
        }
        nv0 = p0; nv1 = p1;
    }

    // per-b argmin: in-register wave butterfly, then 8-candidate combine
    const int wv = t >> 6, lane = t & 63;
    #pragma unroll
    for (int b = 0; b < BB; ++b) {
        float bv = acc0[b]; int bi = t;              // n0 = t
        if (acc1[b] < bv) { bv = acc1[b]; bi = t + 512; }  // strict <: first-min kept (t < t+512)
        #pragma unroll
        for (int off = 32; off; off >>= 1) {
            float ov = __shfl_xor(bv, off);
            int   oi = __shfl_xor(bi, off);
            if (ov < bv || (ov == bv && oi < bi)) { bv = ov; bi = oi; }
        }
        if (lane == 0) { candv[wv][b] = bv; candi[wv][b] = bi; }
    }
    __syncthreads();

    if (t < BB) {
        // combine the 8 wave candidates for b = t (explicit index tie-break)
        float best = candv[0][t]; int bidx = candi[0][t];
        #pragma unroll
        for (int w = 1; w < 8; ++w) {
            float v = candv[w][t]; int i2 = candi[w][t];
            if (v < best || (v == best && i2 < bidx)) { best = v; bidx = i2; }
        }
        bmu_i[t] = bidx;
        bmu_d[t] = sqrtf(best);

        // cls[b] = argmax_c y[b][c] (strict > keeps first, matching jnp.argmax)
        const float* yr = y + (long)(b0 + t) * Cc;
        float bvv = yr[0]; int bc = 0;
        #pragma unroll
        for (int c = 1; c < Cc; ++c) { float v = yr[c]; if (v > bvv) { bvv = v; bc = c; } }
        clss[t] = bc;
        ws_cls[b0 + t] = bc;
    }
    __syncthreads();

    // out rows: labels[bmu[b]]
    if (t < BB * Cc) {
        int b = t / Cc, c = t % Cc;
        out[(long)(b0 + b) * Cc + c] = labels[(long)bmu_i[b] * Cc + c];
    }

    // fold this block's BB b's into per-class partials (static-indexed registers)
    const float sig = sigma[0];
    float accA[Cc], accB[Cc];
    #pragma unroll
    for (int c = 0; c < Cc; ++c) { accA[c] = 0.f; accB[c] = 0.f; }

    #pragma unroll
    for (int b = 0; b < BB; ++b) {
        float gb = expf(-bmu_d[b] / sig);
        int   cl = clss[b];
        float g0 = expf(-sqrtf(acc0[b]) / sig);
        float g1 = expf(-sqrtf(acc1[b]) / sig);
        float gn0 = (gb == 0.f) ? 0.f : g0 / gb;
        float gn1 = (gb == 0.f) ? 0.f : g1 / gb;
        #pragma unroll
        for (int c = 0; c < Cc; ++c) {
            accA[c] += (cl == c) ? gn0 : 0.f;
            accB[c] += (cl == c) ? gn1 : 0.f;
        }
    }

    // c-major partial write: coalesced across t
    float* pb = ws_p + (long)blockIdx.x * (Nn * Cc);
    #pragma unroll
    for (int c = 0; c < Cc; ++c) {
        pb[c * Nn + t]       = accA[c];
        pb[c * Nn + t + 512] = accB[c];
    }
}

// ---------------- final reduction: no atomics, fully deterministic ----------------
__global__ __launch_bounds__(256) void som_fin(
    const float* __restrict__ act_in,
    const int*   __restrict__ cnt_in,
    const float* __restrict__ ws_p,
    const int*   __restrict__ ws_cls,
    float* __restrict__ out)
{
    if (blockIdx.x < 40) {
        const int j = blockIdx.x * 256 + threadIdx.x;  // j = c*Nn + n
        const int c = j >> 10;
        const int n = j & (Nn - 1);
        float s0 = 0.f, s1 = 0.f, s2 = 0.f, s3 = 0.f;
        for (int k = 0; k < NBLK; k += 4) {
            s0 += ws_p[(long)(k + 0) * (Nn * Cc) + j];
            s1 += ws_p[(long)(k + 1) * (Nn * Cc) + j];
            s2 += ws_p[(long)(k + 2) * (Nn * Cc) + j];
            s3 += ws_p[(long)(k + 3) * (Nn * Cc) + j];
        }
        out[ACT_OFF + n * Cc + c] = act_in[n * Cc + c] + ((s0 + s1) + (s2 + s3));
    } else {
        __shared__ int hist[Cc];
        if (threadIdx.x < Cc) hist[threadIdx.x] = 0;
        __syncthreads();
        for (int b = threadIdx.x; b < Bq; b += 256) atomicAdd(&hist[ws_cls[b]], 1);
        __syncthreads();
        if (threadIdx.x < Cc)
            out[CNT_OFF + threadIdx.x] = (float)(cnt_in[threadIdx.x] + hist[threadIdx.x]);
    }
}

// ---------------- fallback path (atomic-based, known-good) ----------------
__global__ void som_init(const float* __restrict__ act_in,
                         const int* __restrict__ cnt_in,
                         float* __restrict__ out) {
    int i = blockIdx.x * blockDim.x + threadIdx.x;
    if (i < Nn * Cc) out[ACT_OFF + i] = act_in[i];
    if (i < Cc) out[CNT_OFF + i] = (float)cnt_in[i];
}

__global__ __launch_bounds__(512) void som_main(
    const float* __restrict__ x,
    const float* __restrict__ y,
    const float* __restrict__ neurons,
    const float* __restrict__ labels,
    const float* __restrict__ sigma,
    float* __restrict__ out)
{
    __shared__ float xs[8][Dd];
    __shared__ float d2s[8][Nn];
    __shared__ float bmu_d[8];
    __shared__ int   bmu_i[8];
    __shared__ int   clss[8];

    const int t  = threadIdx.x;
    const int b0 = blockIdx.x * 8;

    for (int i = t; i < 8 * Dd; i += 512)
        xs[i >> 7][i & (Dd - 1)] = x[b0 * Dd + i];
    __syncthreads();

    float acc0[8], acc1[8];
    #pragma unroll
    for (int b = 0; b < 8; ++b) { acc0[b] = 0.f; acc1[b] = 0.f; }

    const float4* nr0 = (const float4*)(neurons + t * Dd);
    const float4* nr1 = (const float4*)(neurons + (t + 512) * Dd);

    #pragma unroll 2
    for (int dc = 0; dc < Dd / 4; ++dc) {
        float4 nv0 = nr0[dc];
        float4 nv1 = nr1[dc];
        #pragma unroll
        for (int b = 0; b < 8; ++b) {
            float4 xv = *(const float4*)&xs[b][dc * 4];
            float d;
            d = xv.x - nv0.x; acc0[b] = fmaf(d, d, acc0[b]);
            d = xv.y - nv0.y; acc0[b] = fmaf(d, d, acc0[b]);
            d = xv.z - nv0.z; acc0[b] = fmaf(d, d, acc0[b]);
            d = xv.w - nv0.w; acc0[b] = fmaf(d, d, acc0[b]);
            d = xv.x - nv1.x; acc1[b] = fmaf(d, d, acc1[b]);
            d = xv.y - nv1.y; acc1[b] = fmaf(d, d, acc1[b]);
            d = xv.z - nv1.z; acc1[b] = fmaf(d, d, acc1[b]);
            d = xv.w - nv1.w; acc1[b] = fmaf(d, d, acc1[b]);
        }
    }

    #pragma unroll
    for (int b = 0; b < 8; ++b) {
        d2s[b][t]       = acc0[b];
        d2s[b][t + 512] = acc1[b];
    }
    __syncthreads();

    {
        const int wv = t >> 6, lane = t & 63;
        float best = 3.4e38f; int bidx = 0;
        #pragma unroll
        for (int i = 0; i < Nn / 64; ++i) {
            int idx = lane + i * 64;
            float v = d2s[wv][idx];
            if (v < best) { best = v; bidx = idx; }
        }
        #pragma unroll
        for (int off = 32; off; off >>= 1) {
            float ov = __shfl_down(best, off);
            int   oi = __shfl_down(bidx, off);
            if (ov < best || (ov == best && oi < bidx)) { best = ov; bidx = oi; }
        }
        if (lane == 0) { bmu_i[wv] = bidx; bmu_d[wv] = sqrtf(best); }
    }

    if (t < 8) {
        const float* yr = y + (long)(b0 + t) * Cc;
        float bv = yr[0]; int bc = 0;
        #pragma unroll
        for (int c = 1; c < Cc; ++c) { float v = yr[c]; if (v > bv) { bv = v; bc = c; } }
        clss[t] = bc;
        atomicAdd(out + CNT_OFF + bc, 1.0f);
    }
    __syncthreads();

    for (int i = t; i < 8 * Cc; i += 512) {
        int b = i / Cc, c = i % Cc;
        out[(long)(b0 + b) * Cc + c] = labels[(long)bmu_i[b] * Cc + c];
    }

    const float sig = sigma[0];
    #pragma unroll
    for (int b = 0; b < 8; ++b) {
        float gb = expf(-bmu_d[b] / sig);
        int   cl = clss[b];
        float g0 = expf(-sqrtf(acc0[b]) / sig);
        float g1 = expf(-sqrtf(acc1[b]) / sig);
        float gn0 = (gb == 0.f) ? 0.f : g0 / gb;
        float gn1 = (gb == 0.f) ? 0.f : g1 / gb;
        atomicAdd(out + ACT_OFF + t * Cc + cl, gn0);
        atomicAdd(out + ACT_OFF + (t + 512) * Cc + cl, gn1);
    }
}

extern "C" void kernel_launch(void* const* d_in, const int* in_sizes, int n_in,
                              void* d_out, int out_size, void* d_ws, size_t ws_size,
                              hipStream_t stream) {
    const float* x       = (const float*)d_in[0];
    const float* y       = (const float*)d_in[1];
    const float* neurons = (const float*)d_in[2];
    const float* labels  = (const float*)d_in[3];
    const float* act     = (const float*)d_in[4];
    const int*   cnt     = (const int*)d_in[5];
    const float* sigma   = (const float*)d_in[6];
    float* out = (float*)d_out;

    const size_t need = (size_t)WS_NEED_FLOATS * 4;
    if (ws_size >= need) {
        float*  ws_p   = (float*)d_ws;
        int*    ws_cls = (int*)((float*)d_ws + WS_CLS_OFF);
        float4* ws_nt  = (float4*)((float*)d_ws + WS_NT_OFF);
        som_prep<<<32, 256, 0, stream>>>(neurons, ws_nt);
        som_dist<<<NBLK, NTHREADS, 0, stream>>>(x, y, ws_nt, labels, sigma, out, ws_p, ws_cls);
        som_fin<<<41, 256, 0, stream>>>(act, cnt, ws_p, ws_cls, out);
    } else {
        som_init<<<(Nn * Cc + 255) / 256, 256, 0, stream>>>(act, cnt, out);
        som_main<<<Bq / 8, 512, 0, stream>>>(x, y, neurons, labels, sigma, out);
    }
}

// Round 5
// 62.511 us; speedup vs baseline: 1.3122x; 1.3122x over previous
//
#include <hip/hip_runtime.h>
#include <math.h>

#define Bq 2048
#define Nn 1024
#define Dd 128
#define Cc 10
#define BB 8           // batch rows per block
#define NTHREADS 512   // 8 waves
#define NBLK (Bq / BB)               // 256 dist-blocks
#define PART_FLOATS (NBLK * Nn * Cc) // 2.62M floats = 10.5 MB

// d_out layout (floats): [0, B*C) = labels[bmu]; [B*C, B*C+N*C) = activities; last C = counts
#define ACT_OFF (Bq * Cc)
#define CNT_OFF (Bq * Cc + Nn * Cc)

// ws layout (floats): [0, PART) = partials; [PART, PART+Bq) = cls ints;
// then 16B-aligned: nT4 = 32*1024 float4 (512 KB)
#define WS_CLS_OFF PART_FLOATS
#define WS_NT_OFF  ((PART_FLOATS + Bq + 3) & ~3)
#define WS_NEED_FLOATS (WS_NT_OFF + 32 * Nn * 4)

// ---------------- transpose neurons [N][D] -> nT4[dc][n] (float4 of 4 d's) ----------------
__global__ __launch_bounds__(256) void som_prep(
    const float* __restrict__ neurons,
    float4* __restrict__ nt)   // [32][Nn]
{
    __shared__ float tile[32][129];
    const int t    = threadIdx.x;
    const int base = blockIdx.x * 32;   // 32 rows per block

    #pragma unroll
    for (int k = 0; k < 4; ++k) {
        int i  = t + k * 256;           // float4 index in [0,1024)
        int r  = i >> 5;                // row 0..31
        int c4 = i & 31;                // float4-col 0..31
        float4 v = *(const float4*)&neurons[(long)(base + r) * Dd + c4 * 4];
        tile[r][c4 * 4 + 0] = v.x;
        tile[r][c4 * 4 + 1] = v.y;
        tile[r][c4 * 4 + 2] = v.z;
        tile[r][c4 * 4 + 3] = v.w;
    }
    __syncthreads();

    #pragma unroll
    for (int k = 0; k < 4; ++k) {
        int i  = t + k * 256;
        int dc = i >> 5;                // 0..31
        int r  = i & 31;                // consecutive lanes -> consecutive n
        float4 v;
        v.x = tile[r][dc * 4 + 0];
        v.y = tile[r][dc * 4 + 1];
        v.z = tile[r][dc * 4 + 2];
        v.w = tile[r][dc * 4 + 3];
        nt[dc * Nn + base + r] = v;
    }
}

// ---------------- main distance kernel: scalar x, coalesced nt, register argmin ----------------
__global__ __launch_bounds__(NTHREADS) void som_dist(
    const float* __restrict__ x,
    const float* __restrict__ y,
    const float4* __restrict__ nt,    // [32][Nn]
    const float* __restrict__ labels,
    const float* __restrict__ sigma,
    float* __restrict__ out,
    float* __restrict__ ws_p,     // [NBLK][Cc][Nn]
    int*   __restrict__ ws_cls)   // [Bq]
{
    __shared__ float candv[8][BB];
    __shared__ int   candi[8][BB];
    __shared__ float bmu_d[BB];
    __shared__ int   bmu_i[BB];
    __shared__ int   clss[BB];

    const int t  = threadIdx.x;
    const int b0 = blockIdx.x * BB;

    // thread owns neurons n0 = t, n1 = t + 512
    float acc0[BB], acc1[BB];
    #pragma unroll
    for (int b = 0; b < BB; ++b) { acc0[b] = 0.f; acc1[b] = 0.f; }

    #pragma unroll 4
    for (int dc = 0; dc < Dd / 4; ++dc) {
        float4 nv0 = nt[dc * Nn + t];          // coalesced: lane-consecutive n
        float4 nv1 = nt[dc * Nn + t + 512];
        #pragma unroll
        for (int b = 0; b < BB; ++b) {
            // block-uniform address -> scalar load (s_load_dwordx4), no LDS
            float4 xv = *(const float4*)&x[(long)(b0 + b) * Dd + dc * 4];
            float d;
            d = xv.x - nv0.x; acc0[b] = fmaf(d, d, acc0[b]);
            d = xv.y - nv0.y; acc0[b] = fmaf(d, d, acc0[b]);
            d = xv.z - nv0.z; acc0[b] = fmaf(d, d, acc0[b]);
            d = xv.w - nv0.w; acc0[b] = fmaf(d, d, acc0[b]);
            d = xv.x - nv1.x; acc1[b] = fmaf(d, d, acc1[b]);
            d = xv.y - nv1.y; acc1[b] = fmaf(d, d, acc1[b]);
            d = xv.z - nv1.z; acc1[b] = fmaf(d, d, acc1[b]);
            d = xv.w - nv1.w; acc1[b] = fmaf(d, d, acc1[b]);
        }
    }

    // per-b argmin: in-register wave butterfly, then 8-candidate combine
    const int wv = t >> 6, lane = t & 63;
    #pragma unroll
    for (int b = 0; b < BB; ++b) {
        float bv = acc0[b]; int bi = t;                    // n0 = t
        if (acc1[b] < bv) { bv = acc1[b]; bi = t + 512; }  // strict <: first-min kept
        #pragma unroll
        for (int off = 32; off; off >>= 1) {
            float ov = __shfl_xor(bv, off);
            int   oi = __shfl_xor(bi, off);
            if (ov < bv || (ov == bv && oi < bi)) { bv = ov; bi = oi; }
        }
        if (lane == 0) { candv[wv][b] = bv; candi[wv][b] = bi; }
    }
    __syncthreads();

    if (t < BB) {
        // combine the 8 wave candidates for b = t (explicit index tie-break)
        float best = candv[0][t]; int bidx = candi[0][t];
        #pragma unroll
        for (int w = 1; w < 8; ++w) {
            float v = candv[w][t]; int i2 = candi[w][t];
            if (v < best || (v == best && i2 < bidx)) { best = v; bidx = i2; }
        }
        bmu_i[t] = bidx;
        bmu_d[t] = sqrtf(best);

        // cls[b] = argmax_c y[b][c] (strict > keeps first, matching jnp.argmax)
        const float* yr = y + (long)(b0 + t) * Cc;
        float bvv = yr[0]; int bc = 0;
        #pragma unroll
        for (int c = 1; c < Cc; ++c) { float v = yr[c]; if (v > bvv) { bvv = v; bc = c; } }
        clss[t] = bc;
        ws_cls[b0 + t] = bc;
    }
    __syncthreads();

    // out rows: labels[bmu[b]]
    if (t < BB * Cc) {
        int b = t / Cc, c = t % Cc;
        out[(long)(b0 + b) * Cc + c] = labels[(long)bmu_i[b] * Cc + c];
    }

    // fold this block's BB b's into per-class partials (static-indexed registers)
    const float sig = sigma[0];
    float accA[Cc], accB[Cc];
    #pragma unroll
    for (int c = 0; c < Cc; ++c) { accA[c] = 0.f; accB[c] = 0.f; }

    #pragma unroll
    for (int b = 0; b < BB; ++b) {
        float gb = expf(-bmu_d[b] / sig);
        int   cl = clss[b];
        float g0 = expf(-sqrtf(acc0[b]) / sig);
        float g1 = expf(-sqrtf(acc1[b]) / sig);
        float gn0 = (gb == 0.f) ? 0.f : g0 / gb;
        float gn1 = (gb == 0.f) ? 0.f : g1 / gb;
        #pragma unroll
        for (int c = 0; c < Cc; ++c) {
            accA[c] += (cl == c) ? gn0 : 0.f;
            accB[c] += (cl == c) ? gn1 : 0.f;
        }
    }

    // c-major partial write: coalesced across t
    float* pb = ws_p + (long)blockIdx.x * (Nn * Cc);
    #pragma unroll
    for (int c = 0; c < Cc; ++c) {
        pb[c * Nn + t]       = accA[c];
        pb[c * Nn + t + 512] = accB[c];
    }
}

// ---------------- final reduction: no atomics, fully deterministic ----------------
__global__ __launch_bounds__(256) void som_fin(
    const float* __restrict__ act_in,
    const int*   __restrict__ cnt_in,
    const float* __restrict__ ws_p,
    const int*   __restrict__ ws_cls,
    float* __restrict__ out)
{
    if (blockIdx.x < 40) {
        const int j = blockIdx.x * 256 + threadIdx.x;  // j = c*Nn + n
        const int c = j >> 10;
        const int n = j & (Nn - 1);
        float s0 = 0.f, s1 = 0.f, s2 = 0.f, s3 = 0.f;
        float s4 = 0.f, s5 = 0.f, s6 = 0.f, s7 = 0.f;
        for (int k = 0; k < NBLK; k += 8) {
            s0 += ws_p[(long)(k + 0) * (Nn * Cc) + j];
            s1 += ws_p[(long)(k + 1) * (Nn * Cc) + j];
            s2 += ws_p[(long)(k + 2) * (Nn * Cc) + j];
            s3 += ws_p[(long)(k + 3) * (Nn * Cc) + j];
            s4 += ws_p[(long)(k + 4) * (Nn * Cc) + j];
            s5 += ws_p[(long)(k + 5) * (Nn * Cc) + j];
            s6 += ws_p[(long)(k + 6) * (Nn * Cc) + j];
            s7 += ws_p[(long)(k + 7) * (Nn * Cc) + j];
        }
        out[ACT_OFF + n * Cc + c] =
            act_in[n * Cc + c] + (((s0 + s1) + (s2 + s3)) + ((s4 + s5) + (s6 + s7)));
    } else {
        __shared__ int hist[Cc];
        if (threadIdx.x < Cc) hist[threadIdx.x] = 0;
        __syncthreads();
        for (int b = threadIdx.x; b < Bq; b += 256) atomicAdd(&hist[ws_cls[b]], 1);
        __syncthreads();
        if (threadIdx.x < Cc)
            out[CNT_OFF + threadIdx.x] = (float)(cnt_in[threadIdx.x] + hist[threadIdx.x]);
    }
}

// ---------------- fallback path (atomic-based, known-good) ----------------
__global__ void som_init(const float* __restrict__ act_in,
                         const int* __restrict__ cnt_in,
                         float* __restrict__ out) {
    int i = blockIdx.x * blockDim.x + threadIdx.x;
    if (i < Nn * Cc) out[ACT_OFF + i] = act_in[i];
    if (i < Cc) out[CNT_OFF + i] = (float)cnt_in[i];
}

__global__ __launch_bounds__(512) void som_main(
    const float* __restrict__ x,
    const float* __restrict__ y,
    const float* __restrict__ neurons,
    const float* __restrict__ labels,
    const float* __restrict__ sigma,
    float* __restrict__ out)
{
    __shared__ float xs[8][Dd];
    __shared__ float d2s[8][Nn];
    __shared__ float bmu_d[8];
    __shared__ int   bmu_i[8];
    __shared__ int   clss[8];

    const int t  = threadIdx.x;
    const int b0 = blockIdx.x * 8;

    for (int i = t; i < 8 * Dd; i += 512)
        xs[i >> 7][i & (Dd - 1)] = x[b0 * Dd + i];
    __syncthreads();

    float acc0[8], acc1[8];
    #pragma unroll
    for (int b = 0; b < 8; ++b) { acc0[b] = 0.f; acc1[b] = 0.f; }

    const float4* nr0 = (const float4*)(neurons + t * Dd);
    const float4* nr1 = (const float4*)(neurons + (t + 512) * Dd);

    #pragma unroll 2
    for (int dc = 0; dc < Dd / 4; ++dc) {
        float4 nv0 = nr0[dc];
        float4 nv1 = nr1[dc];
        #pragma unroll
        for (int b = 0; b < 8; ++b) {
            float4 xv = *(const float4*)&xs[b][dc * 4];
            float d;
            d = xv.x - nv0.x; acc0[b] = fmaf(d, d, acc0[b]);
            d = xv.y - nv0.y; acc0[b] = fmaf(d, d, acc0[b]);
            d = xv.z - nv0.z; acc0[b] = fmaf(d, d, acc0[b]);
            d = xv.w - nv0.w; acc0[b] = fmaf(d, d, acc0[b]);
            d = xv.x - nv1.x; acc1[b] = fmaf(d, d, acc1[b]);
            d = xv.y - nv1.y; acc1[b] = fmaf(d, d, acc1[b]);
            d = xv.z - nv1.z; acc1[b] = fmaf(d, d, acc1[b]);
            d = xv.w - nv1.w; acc1[b] = fmaf(d, d, acc1[b]);
        }
    }

    #pragma unroll
    for (int b = 0; b < 8; ++b) {
        d2s[b][t]       = acc0[b];
        d2s[b][t + 512] = acc1[b];
    }
    __syncthreads();

    {
        const int wv = t >> 6, lane = t & 63;
        float best = 3.4e38f; int bidx = 0;
        #pragma unroll
        for (int i = 0; i < Nn / 64; ++i) {
            int idx = lane + i * 64;
            float v = d2s[wv][idx];
            if (v < best) { best = v; bidx = idx; }
        }
        #pragma unroll
        for (int off = 32; off; off >>= 1) {
            float ov = __shfl_down(best, off);
            int   oi = __shfl_down(bidx, off);
            if (ov < best || (ov == best && oi < bidx)) { best = ov; bidx = oi; }
        }
        if (lane == 0) { bmu_i[wv] = bidx; bmu_d[wv] = sqrtf(best); }
    }

    if (t < 8) {
        const float* yr = y + (long)(b0 + t) * Cc;
        float bv = yr[0]; int bc = 0;
        #pragma unroll
        for (int c = 1; c < Cc; ++c) { float v = yr[c]; if (v > bv) { bv = v; bc = c; } }
        clss[t] = bc;
        atomicAdd(out + CNT_OFF + bc, 1.0f);
    }
    __syncthreads();

    for (int i = t; i < 8 * Cc; i += 512) {
        int b = i / Cc, c = i % Cc;
        out[(long)(b0 + b) * Cc + c] = labels[(long)bmu_i[b] * Cc + c];
    }

    const float sig = sigma[0];
    #pragma unroll
    for (int b = 0; b < 8; ++b) {
        float gb = expf(-bmu_d[b] / sig);
        int   cl = clss[b];
        float g0 = expf(-sqrtf(acc0[b]) / sig);
        float g1 = expf(-sqrtf(acc1[b]) / sig);
        float gn0 = (gb == 0.f) ? 0.f : g0 / gb;
        float gn1 = (gb == 0.f) ? 0.f : g1 / gb;
        atomicAdd(out + ACT_OFF + t * Cc + cl, gn0);
        atomicAdd(out + ACT_OFF + (t + 512) * Cc + cl, gn1);
    }
}

extern "C" void kernel_launch(void* const* d_in, const int* in_sizes, int n_in,
                              void* d_out, int out_size, void* d_ws, size_t ws_size,
                              hipStream_t stream) {
    const float* x       = (const float*)d_in[0];
    const float* y       = (const float*)d_in[1];
    const float* neurons = (const float*)d_in[2];
    const float* labels  = (const float*)d_in[3];
    const float* act     = (const float*)d_in[4];
    const int*   cnt     = (const int*)d_in[5];
    const float* sigma   = (const float*)d_in[6];
    float* out = (float*)d_out;

    const size_t need = (size_t)WS_NEED_FLOATS * 4;
    if (ws_size >= need) {
        float*  ws_p   = (float*)d_ws;
        int*    ws_cls = (int*)((float*)d_ws + WS_CLS_OFF);
        float4* ws_nt  = (float4*)((float*)d_ws + WS_NT_OFF);
        som_prep<<<32, 256, 0, stream>>>(neurons, ws_nt);
        som_dist<<<NBLK, NTHREADS, 0, stream>>>(x, y, ws_nt, labels, sigma, out, ws_p, ws_cls);
        som_fin<<<41, 256, 0, stream>>>(act, cnt, ws_p, ws_cls, out);
    } else {
        som_init<<<(Nn * Cc + 255) / 256, 256, 0, stream>>>(act, cnt, out);
        som_main<<<Bq / 8, 512, 0, stream>>>(x, y, neurons, labels, sigma, out);
    }
}

// Round 6
// 53.488 us; speedup vs baseline: 1.5336x; 1.1687x over previous
//
#include <hip/hip_runtime.h>
#include <math.h>

#define Bq 2048
#define Nn 1024
#define Dd 128
#define Cc 10
#define BB 8            // batch rows per block
#define NBLK (Bq / BB)               // 256 dist-blocks
#define PART_FLOATS (NBLK * Nn * Cc) // 2.62M floats = 10.5 MB

// d_out layout (floats): [0, B*C) = labels[bmu]; [B*C, B*C+N*C) = activities; last C = counts
#define ACT_OFF (Bq * Cc)
#define CNT_OFF (Bq * Cc + Nn * Cc)

// ws layout (floats): [0, PART) = partials; [PART, PART+Bq) = cls ints;
// then 16B-aligned: nT4 = 32*1024 float4 (512 KB)
#define WS_CLS_OFF PART_FLOATS
#define WS_NT_OFF  ((PART_FLOATS + Bq + 3) & ~3)
#define WS_NEED_FLOATS (WS_NT_OFF + 32 * Nn * 4)

// ---------------- transpose neurons [N][D] -> nT4[dc][n] (float4 of 4 d's) ----------------
__global__ __launch_bounds__(256) void som_prep(
    const float* __restrict__ neurons,
    float4* __restrict__ nt)   // [32][Nn]
{
    __shared__ float tile[32][129];
    const int t    = threadIdx.x;
    const int base = blockIdx.x * 32;   // 32 rows per block

    #pragma unroll
    for (int k = 0; k < 4; ++k) {
        int i  = t + k * 256;           // float4 index in [0,1024)
        int r  = i >> 5;                // row 0..31
        int c4 = i & 31;                // float4-col 0..31
        float4 v = *(const float4*)&neurons[(long)(base + r) * Dd + c4 * 4];
        tile[r][c4 * 4 + 0] = v.x;
        tile[r][c4 * 4 + 1] = v.y;
        tile[r][c4 * 4 + 2] = v.z;
        tile[r][c4 * 4 + 3] = v.w;
    }
    __syncthreads();

    #pragma unroll
    for (int k = 0; k < 4; ++k) {
        int i  = t + k * 256;
        int dc = i >> 5;                // 0..31
        int r  = i & 31;                // consecutive lanes -> consecutive n
        float4 v;
        v.x = tile[r][dc * 4 + 0];
        v.y = tile[r][dc * 4 + 1];
        v.z = tile[r][dc * 4 + 2];
        v.w = tile[r][dc * 4 + 3];
        nt[dc * Nn + base + r] = v;
    }
}

// ---------------- main distance kernel: 1024 threads, 1 neuron/thread ----------------
__global__ __launch_bounds__(1024) void som_dist(
    const float* __restrict__ x,
    const float* __restrict__ y,
    const float4* __restrict__ nt,    // [32][Nn]
    const float* __restrict__ labels,
    const float* __restrict__ sigma,
    float* __restrict__ out,
    float* __restrict__ ws_p,     // [NBLK][Cc][Nn]
    int*   __restrict__ ws_cls)   // [Bq]
{
    __shared__ float candv[16][BB];
    __shared__ int   candi[16][BB];
    __shared__ float bmu_d[BB];
    __shared__ int   bmu_i[BB];
    __shared__ int   clss[BB];

    const int t  = threadIdx.x;          // owns neuron n = t
    const int b0 = blockIdx.x * BB;

    float acc[BB];
    #pragma unroll
    for (int b = 0; b < BB; ++b) acc[b] = 0.f;

    #pragma unroll 8
    for (int dc = 0; dc < Dd / 4; ++dc) {
        float4 nv = nt[dc * Nn + t];     // coalesced: lane-consecutive n
        #pragma unroll
        for (int b = 0; b < BB; ++b) {
            // block-uniform address -> scalar load (s_load_dwordx4)
            float4 xv = *(const float4*)&x[(b0 + b) * Dd + dc * 4];
            float d;
            d = xv.x - nv.x; acc[b] = fmaf(d, d, acc[b]);
            d = xv.y - nv.y; acc[b] = fmaf(d, d, acc[b]);
            d = xv.z - nv.z; acc[b] = fmaf(d, d, acc[b]);
            d = xv.w - nv.w; acc[b] = fmaf(d, d, acc[b]);
        }
    }

    // per-b argmin: wave butterfly over 64 neurons, then 16-wave combine
    const int wv = t >> 6, lane = t & 63;
    #pragma unroll
    for (int b = 0; b < BB; ++b) {
        float bv = acc[b]; int bi = t;
        #pragma unroll
        for (int off = 32; off; off >>= 1) {
            float ov = __shfl_xor(bv, off);
            int   oi = __shfl_xor(bi, off);
            if (ov < bv || (ov == bv && oi < bi)) { bv = ov; bi = oi; }
        }
        if (lane == 0) { candv[wv][b] = bv; candi[wv][b] = bi; }
    }
    __syncthreads();

    if (t < BB) {
        // combine the 16 wave candidates for b = t (explicit index tie-break)
        float best = candv[0][t]; int bidx = candi[0][t];
        #pragma unroll
        for (int w = 1; w < 16; ++w) {
            float v = candv[w][t]; int i2 = candi[w][t];
            if (v < best || (v == best && i2 < bidx)) { best = v; bidx = i2; }
        }
        bmu_i[t] = bidx;
        bmu_d[t] = sqrtf(best);

        // cls[b] = argmax_c y[b][c] (strict > keeps first, matching jnp.argmax)
        const float* yr = y + (long)(b0 + t) * Cc;
        float bvv = yr[0]; int bc = 0;
        #pragma unroll
        for (int c = 1; c < Cc; ++c) { float v = yr[c]; if (v > bvv) { bvv = v; bc = c; } }
        clss[t] = bc;
        ws_cls[b0 + t] = bc;
    }
    __syncthreads();

    // out rows: labels[bmu[b]]
    if (t < BB * Cc) {
        int b = t / Cc, c = t % Cc;
        out[(b0 + b) * Cc + c] = labels[bmu_i[b] * Cc + c];
    }

    // fold this block's BB b's into per-class partials (static-indexed registers)
    const float sig = sigma[0];
    float accA[Cc];
    #pragma unroll
    for (int c = 0; c < Cc; ++c) accA[c] = 0.f;

    #pragma unroll
    for (int b = 0; b < BB; ++b) {
        float gb = expf(-bmu_d[b] / sig);
        int   cl = clss[b];
        float g  = expf(-sqrtf(acc[b]) / sig);
        float gn = (gb == 0.f) ? 0.f : g / gb;
        #pragma unroll
        for (int c = 0; c < Cc; ++c) accA[c] += (cl == c) ? gn : 0.f;
    }

    // c-major partial write: coalesced across t
    float* pb = ws_p + (long)blockIdx.x * (Nn * Cc);
    #pragma unroll
    for (int c = 0; c < Cc; ++c) pb[c * Nn + t] = accA[c];
}

// ---------------- final reduction: 160 j-blocks x 4 k-chunks, no atomics ----------------
__global__ __launch_bounds__(256) void som_fin(
    const float* __restrict__ act_in,
    const int*   __restrict__ cnt_in,
    const float* __restrict__ ws_p,
    const int*   __restrict__ ws_cls,
    float* __restrict__ out)
{
    if (blockIdx.x < 160) {
        const int t  = threadIdx.x;
        const int kc = t & 3;                       // k-chunk 0..3 (64 partials each)
        const int j  = blockIdx.x * 64 + (t >> 2);  // j = c*Nn + n
        const int c  = j >> 10;
        const int n  = j & (Nn - 1);
        const float* p = ws_p + (long)(kc * 64) * (Nn * Cc) + j;
        float s = 0.f;
        #pragma unroll 8
        for (int i = 0; i < 64; ++i) s += p[(long)i * (Nn * Cc)];
        // combine the 4 k-chunks (lanes kc=0..3 of the same j)
        s += __shfl_down(s, 2);
        s += __shfl_down(s, 1);
        if (kc == 0) out[ACT_OFF + n * Cc + c] = act_in[n * Cc + c] + s;
    } else {
        __shared__ int hist[Cc];
        if (threadIdx.x < Cc) hist[threadIdx.x] = 0;
        __syncthreads();
        for (int b = threadIdx.x; b < Bq; b += 256) atomicAdd(&hist[ws_cls[b]], 1);
        __syncthreads();
        if (threadIdx.x < Cc)
            out[CNT_OFF + threadIdx.x] = (float)(cnt_in[threadIdx.x] + hist[threadIdx.x]);
    }
}

// ---------------- fallback path (atomic-based, known-good) ----------------
__global__ void som_init(const float* __restrict__ act_in,
                         const int* __restrict__ cnt_in,
                         float* __restrict__ out) {
    int i = blockIdx.x * blockDim.x + threadIdx.x;
    if (i < Nn * Cc) out[ACT_OFF + i] = act_in[i];
    if (i < Cc) out[CNT_OFF + i] = (float)cnt_in[i];
}

__global__ __launch_bounds__(512) void som_main(
    const float* __restrict__ x,
    const float* __restrict__ y,
    const float* __restrict__ neurons,
    const float* __restrict__ labels,
    const float* __restrict__ sigma,
    float* __restrict__ out)
{
    __shared__ float xs[8][Dd];
    __shared__ float d2s[8][Nn];
    __shared__ float bmu_d[8];
    __shared__ int   bmu_i[8];
    __shared__ int   clss[8];

    const int t  = threadIdx.x;
    const int b0 = blockIdx.x * 8;

    for (int i = t; i < 8 * Dd; i += 512)
        xs[i >> 7][i & (Dd - 1)] = x[b0 * Dd + i];
    __syncthreads();

    float acc0[8], acc1[8];
    #pragma unroll
    for (int b = 0; b < 8; ++b) { acc0[b] = 0.f; acc1[b] = 0.f; }

    const float4* nr0 = (const float4*)(neurons + t * Dd);
    const float4* nr1 = (const float4*)(neurons + (t + 512) * Dd);

    #pragma unroll 2
    for (int dc = 0; dc < Dd / 4; ++dc) {
        float4 nv0 = nr0[dc];
        float4 nv1 = nr1[dc];
        #pragma unroll
        for (int b = 0; b < 8; ++b) {
            float4 xv = *(const float4*)&xs[b][dc * 4];
            float d;
            d = xv.x - nv0.x; acc0[b] = fmaf(d, d, acc0[b]);
            d = xv.y - nv0.y; acc0[b] = fmaf(d, d, acc0[b]);
            d = xv.z - nv0.z; acc0[b] = fmaf(d, d, acc0[b]);
            d = xv.w - nv0.w; acc0[b] = fmaf(d, d, acc0[b]);
            d = xv.x - nv1.x; acc1[b] = fmaf(d, d, acc1[b]);
            d = xv.y - nv1.y; acc1[b] = fmaf(d, d, acc1[b]);
            d = xv.z - nv1.z; acc1[b] = fmaf(d, d, acc1[b]);
            d = xv.w - nv1.w; acc1[b] = fmaf(d, d, acc1[b]);
        }
    }

    #pragma unroll
    for (int b = 0; b < 8; ++b) {
        d2s[b][t]       = acc0[b];
        d2s[b][t + 512] = acc1[b];
    }
    __syncthreads();

    {
        const int wv = t >> 6, lane = t & 63;
        float best = 3.4e38f; int bidx = 0;
        #pragma unroll
        for (int i = 0; i < Nn / 64; ++i) {
            int idx = lane + i * 64;
            float v = d2s[wv][idx];
            if (v < best) { best = v; bidx = idx; }
        }
        #pragma unroll
        for (int off = 32; off; off >>= 1) {
            float ov = __shfl_down(best, off);
            int   oi = __shfl_down(bidx, off);
            if (ov < best || (ov == best && oi < bidx)) { best = ov; bidx = oi; }
        }
        if (lane == 0) { bmu_i[wv] = bidx; bmu_d[wv] = sqrtf(best); }
    }

    if (t < 8) {
        const float* yr = y + (long)(b0 + t) * Cc;
        float bv = yr[0]; int bc = 0;
        #pragma unroll
        for (int c = 1; c < Cc; ++c) { float v = yr[c]; if (v > bv) { bv = v; bc = c; } }
        clss[t] = bc;
        atomicAdd(out + CNT_OFF + bc, 1.0f);
    }
    __syncthreads();

    for (int i = t; i < 8 * Cc; i += 512) {
        int b = i / Cc, c = i % Cc;
        out[(long)(b0 + b) * Cc + c] = labels[(long)bmu_i[b] * Cc + c];
    }

    const float sig = sigma[0];
    #pragma unroll
    for (int b = 0; b < 8; ++b) {
        float gb = expf(-bmu_d[b] / sig);
        int   cl = clss[b];
        float g0 = expf(-sqrtf(acc0[b]) / sig);
        float g1 = expf(-sqrtf(acc1[b]) / sig);
        float gn0 = (gb == 0.f) ? 0.f : g0 / gb;
        float gn1 = (gb == 0.f) ? 0.f : g1 / gb;
        atomicAdd(out + ACT_OFF + t * Cc + cl, gn0);
        atomicAdd(out + ACT_OFF + (t + 512) * Cc + cl, gn1);
    }
}

extern "C" void kernel_launch(void* const* d_in, const int* in_sizes, int n_in,
                              void* d_out, int out_size, void* d_ws, size_t ws_size,
                              hipStream_t stream) {
    const float* x       = (const float*)d_in[0];
    const float* y       = (const float*)d_in[1];
    const float* neurons = (const float*)d_in[2];
    const float* labels  = (const float*)d_in[3];
    const float* act     = (const float*)d_in[4];
    const int*   cnt     = (const int*)d_in[5];
    const float* sigma   = (const float*)d_in[6];
    float* out = (float*)d_out;

    const size_t need = (size_t)WS_NEED_FLOATS * 4;
    if (ws_size >= need) {
        float*  ws_p   = (float*)d_ws;
        int*    ws_cls = (int*)((float*)d_ws + WS_CLS_OFF);
        float4* ws_nt  = (float4*)((float*)d_ws + WS_NT_OFF);
        som_prep<<<32, 256, 0, stream>>>(neurons, ws_nt);
        som_dist<<<NBLK, 1024, 0, stream>>>(x, y, ws_nt, labels, sigma, out, ws_p, ws_cls);
        som_fin<<<161, 256, 0, stream>>>(act, cnt, ws_p, ws_cls, out);
    } else {
        som_init<<<(Nn * Cc + 255) / 256, 256, 0, stream>>>(act, cnt, out);
        som_main<<<Bq / 8, 512, 0, stream>>>(x, y, neurons, labels, sigma, out);
    }
}

// Round 7
// 42.914 us; speedup vs baseline: 1.9115x; 1.2464x over previous
//
#include <hip/hip_runtime.h>
#include <math.h>

#define Bq 2048
#define Nn 1024
#define Dd 128
#define Cc 10
#define BB 8            // batch rows per block
#define NBLK (Bq / BB)               // 256 dist-blocks
#define PART_FLOATS (NBLK * Nn * Cc) // 2.62M floats = 10.5 MB

// d_out layout (floats): [0, B*C) = labels[bmu]; [B*C, B*C+N*C) = activities; last C = counts
#define ACT_OFF (Bq * Cc)
#define CNT_OFF (Bq * Cc + Nn * Cc)

// ws layout (floats): [0, PART) = partials; [PART, PART+Bq) = cls ints;
// 16B-aligned: nT4 = 32*1024 float4 (512 KB); then ns2 = 1024 floats
#define WS_CLS_OFF PART_FLOATS
#define WS_NT_OFF  ((PART_FLOATS + Bq + 3) & ~3)
#define WS_NS2_OFF (WS_NT_OFF + 32 * Nn * 4)
#define WS_NEED_FLOATS (WS_NS2_OFF + Nn)

// ---------------- prep: transpose neurons [N][D] -> nT4[dc][n], and ns2[n] ----------------
__global__ __launch_bounds__(256) void som_prep(
    const float* __restrict__ neurons,
    float4* __restrict__ nt,    // [32][Nn]
    float* __restrict__ ns2)    // [Nn]
{
    __shared__ float tile[32][129];
    const int t    = threadIdx.x;
    const int base = blockIdx.x * 32;   // 32 rows per block

    #pragma unroll
    for (int k = 0; k < 4; ++k) {
        int i  = t + k * 256;           // float4 index in [0,1024)
        int r  = i >> 5;                // row 0..31
        int c4 = i & 31;                // float4-col 0..31
        float4 v = *(const float4*)&neurons[(long)(base + r) * Dd + c4 * 4];
        tile[r][c4 * 4 + 0] = v.x;
        tile[r][c4 * 4 + 1] = v.y;
        tile[r][c4 * 4 + 2] = v.z;
        tile[r][c4 * 4 + 3] = v.w;
    }
    __syncthreads();

    // transposed write
    #pragma unroll
    for (int k = 0; k < 4; ++k) {
        int i  = t + k * 256;
        int dc = i >> 5;                // 0..31
        int r  = i & 31;                // consecutive lanes -> consecutive n
        float4 v;
        v.x = tile[r][dc * 4 + 0];
        v.y = tile[r][dc * 4 + 1];
        v.z = tile[r][dc * 4 + 2];
        v.w = tile[r][dc * 4 + 3];
        nt[dc * Nn + base + r] = v;
    }

    // ns2: row = t>>3, seg = t&7 (16 elems each), 8-lane shfl combine
    {
        int r   = t >> 3;
        int seg = t & 7;
        float s = 0.f;
        #pragma unroll
        for (int i = 0; i < 16; ++i) {
            float v = tile[r][seg * 16 + i];
            s = fmaf(v, v, s);
        }
        s += __shfl_down(s, 4);
        s += __shfl_down(s, 2);
        s += __shfl_down(s, 1);
        if (seg == 0) ns2[base + r] = s;
    }
}

// ---------------- main distance kernel: dot-form, 1024 threads, 1 neuron/thread ----------------
__global__ __launch_bounds__(1024) void som_dist(
    const float* __restrict__ x,
    const float* __restrict__ y,
    const float4* __restrict__ nt,    // [32][Nn]
    const float* __restrict__ ns2,    // [Nn]
    const float* __restrict__ labels,
    const float* __restrict__ sigma,
    float* __restrict__ out,
    float* __restrict__ ws_p,     // [NBLK][Cc][Nn]
    int*   __restrict__ ws_cls)   // [Bq]
{
    __shared__ float candv[16][BB];
    __shared__ int   candi[16][BB];
    __shared__ float xs2s[BB];
    __shared__ float bmu_d[BB];
    __shared__ int   bmu_i[BB];
    __shared__ int   clss[BB];

    const int t  = threadIdx.x;          // owns neuron n = t
    const int b0 = blockIdx.x * BB;
    const int wv = t >> 6, lane = t & 63;

    // xs2[b]: wave w (w<8) computes |x[b0+w]|^2 (order-independent of argmin)
    if (wv < BB) {
        float v0 = x[(b0 + wv) * Dd + lane];
        float v1 = x[(b0 + wv) * Dd + lane + 64];
        float s  = fmaf(v0, v0, v1 * v1);
        #pragma unroll
        for (int off = 32; off; off >>= 1) s += __shfl_xor(s, off);
        if (lane == 0) xs2s[wv] = s;
    }

    // dot products: acc[b] = x[b] . n[t]
    float acc[BB];
    #pragma unroll
    for (int b = 0; b < BB; ++b) acc[b] = 0.f;

    float4 nv = nt[t];
    #pragma unroll 4
    for (int dc = 0; dc < Dd / 4; ++dc) {
        float4 nv_n;
        if (dc + 1 < Dd / 4) nv_n = nt[(dc + 1) * Nn + t];
        #pragma unroll
        for (int b = 0; b < BB; ++b) {
            // block-uniform address -> scalar loads
            float4 xv = *(const float4*)&x[(b0 + b) * Dd + dc * 4];
            acc[b] = fmaf(xv.x, nv.x, acc[b]);
            acc[b] = fmaf(xv.y, nv.y, acc[b]);
            acc[b] = fmaf(xv.z, nv.z, acc[b]);
            acc[b] = fmaf(xv.w, nv.w, acc[b]);
        }
        nv = nv_n;
    }

    // shifted distance v[b] = ns2[n] - 2*dot  (argmin over n unaffected by +xs2[b])
    const float ns2v = ns2[t];
    float dv[BB];
    #pragma unroll
    for (int b = 0; b < BB; ++b) dv[b] = fmaf(-2.f, acc[b], ns2v);

    // per-b argmin: wave butterfly over 64 lanes, then 16-wave combine
    #pragma unroll
    for (int b = 0; b < BB; ++b) {
        float bv = dv[b]; int bi = t;
        #pragma unroll
        for (int off = 32; off; off >>= 1) {
            float ov = __shfl_xor(bv, off);
            int   oi = __shfl_xor(bi, off);
            if (ov < bv || (ov == bv && oi < bi)) { bv = ov; bi = oi; }
        }
        if (lane == 0) { candv[wv][b] = bv; candi[wv][b] = bi; }
    }
    __syncthreads();

    if (t < BB) {
        float best = candv[0][t]; int bidx = candi[0][t];
        #pragma unroll
        for (int w = 1; w < 16; ++w) {
            float v = candv[w][t]; int i2 = candi[w][t];
            if (v < best || (v == best && i2 < bidx)) { best = v; bidx = i2; }
        }
        bmu_i[t] = bidx;
        float d2 = xs2s[t] + best;
        bmu_d[t] = sqrtf(d2 > 0.f ? d2 : 0.f);

        // cls[b] = argmax_c y[b][c] (strict > keeps first, matching jnp.argmax)
        const float* yr = y + (long)(b0 + t) * Cc;
        float bvv = yr[0]; int bc = 0;
        #pragma unroll
        for (int c = 1; c < Cc; ++c) { float v = yr[c]; if (v > bvv) { bvv = v; bc = c; } }
        clss[t] = bc;
        ws_cls[b0 + t] = bc;
    }
    __syncthreads();

    // out rows: labels[bmu[b]]
    if (t < BB * Cc) {
        int b = t / Cc, c = t % Cc;
        out[(b0 + b) * Cc + c] = labels[bmu_i[b] * Cc + c];
    }

    // fold this block's BB b's into per-class partials (static-indexed registers)
    const float sig = sigma[0];
    float accA[Cc];
    #pragma unroll
    for (int c = 0; c < Cc; ++c) accA[c] = 0.f;

    #pragma unroll
    for (int b = 0; b < BB; ++b) {
        float gb = expf(-bmu_d[b] / sig);
        int   cl = clss[b];
        float d2 = xs2s[b] + dv[b];
        float g  = expf(-sqrtf(d2 > 0.f ? d2 : 0.f) / sig);
        float gn = (gb == 0.f) ? 0.f : g / gb;
        #pragma unroll
        for (int c = 0; c < Cc; ++c) accA[c] += (cl == c) ? gn : 0.f;
    }

    // c-major partial write: coalesced across t
    float* pb = ws_p + (long)blockIdx.x * (Nn * Cc);
    #pragma unroll
    for (int c = 0; c < Cc; ++c) pb[c * Nn + t] = accA[c];
}

// ---------------- final reduction: 160 j-blocks x 4 k-chunks, no atomics ----------------
__global__ __launch_bounds__(256) void som_fin(
    const float* __restrict__ act_in,
    const int*   __restrict__ cnt_in,
    const float* __restrict__ ws_p,
    const int*   __restrict__ ws_cls,
    float* __restrict__ out)
{
    if (blockIdx.x < 160) {
        const int t  = threadIdx.x;
        const int kc = t & 3;                       // k-chunk 0..3 (64 partials each)
        const int j  = blockIdx.x * 64 + (t >> 2);  // j = c*Nn + n
        const int c  = j >> 10;
        const int n  = j & (Nn - 1);
        const float* p = ws_p + (long)(kc * 64) * (Nn * Cc) + j;
        float s = 0.f;
        #pragma unroll 8
        for (int i = 0; i < 64; ++i) s += p[(long)i * (Nn * Cc)];
        s += __shfl_down(s, 2);
        s += __shfl_down(s, 1);
        if (kc == 0) out[ACT_OFF + n * Cc + c] = act_in[n * Cc + c] + s;
    } else {
        __shared__ int hist[Cc];
        if (threadIdx.x < Cc) hist[threadIdx.x] = 0;
        __syncthreads();
        for (int b = threadIdx.x; b < Bq; b += 256) atomicAdd(&hist[ws_cls[b]], 1);
        __syncthreads();
        if (threadIdx.x < Cc)
            out[CNT_OFF + threadIdx.x] = (float)(cnt_in[threadIdx.x] + hist[threadIdx.x]);
    }
}

// ---------------- fallback path (atomic-based, known-good) ----------------
__global__ void som_init(const float* __restrict__ act_in,
                         const int* __restrict__ cnt_in,
                         float* __restrict__ out) {
    int i = blockIdx.x * blockDim.x + threadIdx.x;
    if (i < Nn * Cc) out[ACT_OFF + i] = act_in[i];
    if (i < Cc) out[CNT_OFF + i] = (float)cnt_in[i];
}

__global__ __launch_bounds__(512) void som_main(
    const float* __restrict__ x,
    const float* __restrict__ y,
    const float* __restrict__ neurons,
    const float* __restrict__ labels,
    const float* __restrict__ sigma,
    float* __restrict__ out)
{
    __shared__ float xs[8][Dd];
    __shared__ float d2s[8][Nn];
    __shared__ float bmu_d[8];
    __shared__ int   bmu_i[8];
    __shared__ int   clss[8];

    const int t  = threadIdx.x;
    const int b0 = blockIdx.x * 8;

    for (int i = t; i < 8 * Dd; i += 512)
        xs[i >> 7][i & (Dd - 1)] = x[b0 * Dd + i];
    __syncthreads();

    float acc0[8], acc1[8];
    #pragma unroll
    for (int b = 0; b < 8; ++b) { acc0[b] = 0.f; acc1[b] = 0.f; }

    const float4* nr0 = (const float4*)(neurons + t * Dd);
    const float4* nr1 = (const float4*)(neurons + (t + 512) * Dd);

    #pragma unroll 2
    for (int dc = 0; dc < Dd / 4; ++dc) {
        float4 nv0 = nr0[dc];
        float4 nv1 = nr1[dc];
        #pragma unroll
        for (int b = 0; b < 8; ++b) {
            float4 xv = *(const float4*)&xs[b][dc * 4];
            float d;
            d = xv.x - nv0.x; acc0[b] = fmaf(d, d, acc0[b]);
            d = xv.y - nv0.y; acc0[b] = fmaf(d, d, acc0[b]);
            d = xv.z - nv0.z; acc0[b] = fmaf(d, d, acc0[b]);
            d = xv.w - nv0.w; acc0[b] = fmaf(d, d, acc0[b]);
            d = xv.x - nv1.x; acc1[b] = fmaf(d, d, acc1[b]);
            d = xv.y - nv1.y; acc1[b] = fmaf(d, d, acc1[b]);
            d = xv.z - nv1.z; acc1[b] = fmaf(d, d, acc1[b]);
            d = xv.w - nv1.w; acc1[b] = fmaf(d, d, acc1[b]);
        }
    }

    #pragma unroll
    for (int b = 0; b < 8; ++b) {
        d2s[b][t]       = acc0[b];
        d2s[b][t + 512] = acc1[b];
    }
    __syncthreads();

    {
        const int wv = t >> 6, lane = t & 63;
        float best = 3.4e38f; int bidx = 0;
        #pragma unroll
        for (int i = 0; i < Nn / 64; ++i) {
            int idx = lane + i * 64;
            float v = d2s[wv][idx];
            if (v < best) { best = v; bidx = idx; }
        }
        #pragma unroll
        for (int off = 32; off; off >>= 1) {
            float ov = __shfl_down(best, off);
            int   oi = __shfl_down(bidx, off);
            if (ov < best || (ov == best && oi < bidx)) { best = ov; bidx = oi; }
        }
        if (lane == 0) { bmu_i[wv] = bidx; bmu_d[wv] = sqrtf(best); }
    }

    if (t < 8) {
        const float* yr = y + (long)(b0 + t) * Cc;
        float bv = yr[0]; int bc = 0;
        #pragma unroll
        for (int c = 1; c < Cc; ++c) { float v = yr[c]; if (v > bv) { bv = v; bc = c; } }
        clss[t] = bc;
        atomicAdd(out + CNT_OFF + bc, 1.0f);
    }
    __syncthreads();

    for (int i = t; i < 8 * Cc; i += 512) {
        int b = i / Cc, c = i % Cc;
        out[(long)(b0 + b) * Cc + c] = labels[(long)bmu_i[b] * Cc + c];
    }

    const float sig = sigma[0];
    #pragma unroll
    for (int b = 0; b < 8; ++b) {
        float gb = expf(-bmu_d[b] / sig);
        int   cl = clss[b];
        float g0 = expf(-sqrtf(acc0[b]) / sig);
        float g1 = expf(-sqrtf(acc1[b]) / sig);
        float gn0 = (gb == 0.f) ? 0.f : g0 / gb;
        float gn1 = (gb == 0.f) ? 0.f : g1 / gb;
        atomicAdd(out + ACT_OFF + t * Cc + cl, gn0);
        atomicAdd(out + ACT_OFF + (t + 512) * Cc + cl, gn1);
    }
}

extern "C" void kernel_launch(void* const* d_in, const int* in_sizes, int n_in,
                              void* d_out, int out_size, void* d_ws, size_t ws_size,
                              hipStream_t stream) {
    const float* x       = (const float*)d_in[0];
    const float* y       = (const float*)d_in[1];
    const float* neurons = (const float*)d_in[2];
    const float* labels  = (const float*)d_in[3];
    const float* act     = (const float*)d_in[4];
    const int*   cnt     = (const int*)d_in[5];
    const float* sigma   = (const float*)d_in[6];
    float* out = (float*)d_out;

    const size_t need = (size_t)WS_NEED_FLOATS * 4;
    if (ws_size >= need) {
        float*  ws_p   = (float*)d_ws;
        int*    ws_cls = (int*)((float*)d_ws + WS_CLS_OFF);
        float4* ws_nt  = (float4*)((float*)d_ws + WS_NT_OFF);
        float*  ws_ns2 = (float*)d_ws + WS_NS2_OFF;
        som_prep<<<32, 256, 0, stream>>>(neurons, ws_nt, ws_ns2);
        som_dist<<<NBLK, 1024, 0, stream>>>(x, y, ws_nt, ws_ns2, labels, sigma, out, ws_p, ws_cls);
        som_fin<<<161, 256, 0, stream>>>(act, cnt, ws_p, ws_cls, out);
    } else {
        som_init<<<(Nn * Cc + 255) / 256, 256, 0, stream>>>(act, cnt, out);
        som_main<<<Bq / 8, 512, 0, stream>>>(x, y, neurons, labels, sigma, out);
    }
}